// Round 10
// baseline (232.789 us; speedup 1.0000x reference)
//
#include <hip/hip_runtime.h>
#include <hip/hip_bf16.h>

// MultiHeadAttention: B=4, T=2048, D=512, H=8, K=64.
// Inputs fp32, output fp32, intermediates bf16. THREE kernels:
// [1] gemm1f: qkv = x @ w_qkv^T, fp32 inputs converted during staging (fused cvt)
// [2] attn_v4: causal flash attention, Q-tile 128 (8 waves), s-tile 64
// [3] gemm_b64: out = attn @ w_proj^T + b_proj (fp32 out)

typedef unsigned short u16;
typedef __attribute__((ext_vector_type(8))) __bf16 bf16x8;
typedef __attribute__((ext_vector_type(8))) unsigned short u16x8;
typedef __attribute__((ext_vector_type(4))) float f32x4;
typedef __attribute__((ext_vector_type(4))) unsigned u32x4;

#define DEV static __device__ __forceinline__

DEV void async16(const u16* g, u16* l) {  // global->LDS DMA, 16B/lane
  __builtin_amdgcn_global_load_lds(
      (const __attribute__((address_space(1))) unsigned int*)g,
      (__attribute__((address_space(3))) unsigned int*)l, 16, 0, 0);
}
DEV u16x8 gld8(const u16* p) { return *(const u16x8*)p; }
DEV void lst8(u16* p, u16x8 v) { *(u16x8*)p = v; }
DEV bf16x8 ldsld8(const u16* p) {
  return __builtin_bit_cast(bf16x8, *(const u16x8*)p);
}
DEV f32x4 mfma16(bf16x8 a, bf16x8 b, f32x4 c) {
  return __builtin_amdgcn_mfma_f32_16x16x32_bf16(a, b, c, 0, 0, 0);
}
DEV u16 f2b(float f) {  // fp32 -> bf16 RNE
  unsigned u = __builtin_bit_cast(unsigned, f);
  u += 0x7FFFu + ((u >> 16) & 1u);
  return (u16)(u >> 16);
}
DEV unsigned pk2(float x, float y) {  // v_cvt_pk_bf16_f32
  __hip_bfloat162 t = __float22bfloat162_rn(float2{x, y});
  unsigned r;
  __builtin_memcpy(&r, &t, 4);
  return r;
}
DEV u16x8 pack8(f32x4 a, f32x4 b) {  // 8x fp32 -> bf16
  u32x4 t;
  t[0] = pk2(a[0], a[1]);
  t[1] = pk2(a[2], a[3]);
  t[2] = pk2(b[0], b[1]);
  t[3] = pk2(b[2], b[3]);
  return __builtin_bit_cast(u16x8, t);
}

// ---------------------------------------------------------------------------
// gemm1f: C[M,1536](bf16) = x[M,512](fp32) @ w_qkv[1536,512](fp32)^T.
// Fused fp32->bf16 conversion during register staging (no cvt kernel, no xb).
// BM=BN=128, BK=64 as two 32-col halves; 4 waves 2x2, 4x4 frags of 16x16x32.
// ---------------------------------------------------------------------------
__global__ void gemm1f(const float* __restrict__ A, const float* __restrict__ Bt,
                       u16* __restrict__ C, int N, int K) {
  __shared__ __align__(16) u16 As[2][128 * 32];
  __shared__ __align__(16) u16 Bs[2][128 * 32];

  const int t = threadIdx.x, lane = t & 63, w = t >> 6;
  const int lane15 = lane & 15, quad = lane >> 4;
  const int wr = w >> 1, wc = w & 1;
  const long row0 = (long)blockIdx.y * 128;
  const int col0 = blockIdx.x * 128;

  const int sr = t >> 2, sc = (t & 3) * 8;
  const float* Ag = A + (row0 + sr) * (long)K + sc;
  const float* Bg = Bt + (long)(col0 + sr) * K + sc;
  u16* AsD[2][2];
  u16* BsD[2][2];
#pragma unroll
  for (int r = 0; r < 2; r++)
#pragma unroll
    for (int hf = 0; hf < 2; hf++) {
      AsD[r][hf] = &As[hf][(sr + r * 64) * 32 + sc];
      BsD[r][hf] = &Bs[hf][(sr + r * 64) * 32 + sc];
    }

  f32x4 acc[4][4];
#pragma unroll
  for (int i = 0; i < 4; i++)
#pragma unroll
    for (int j = 0; j < 4; j++) acc[i][j] = (f32x4)(0.0f);

  // prefetch k-chunk 0, packed to bf16 in regs
  u16x8 ra[2][2], rb[2][2];
#pragma unroll
  for (int r = 0; r < 2; r++)
#pragma unroll
    for (int hf = 0; hf < 2; hf++) {
      const float* pa = Ag + (long)r * 64 * K + hf * 32;
      const float* pb = Bg + (long)r * 64 * K + hf * 32;
      ra[r][hf] = pack8(*(const f32x4*)pa, *(const f32x4*)(pa + 4));
      rb[r][hf] = pack8(*(const f32x4*)pb, *(const f32x4*)(pb + 4));
    }

  for (int k0 = 0; k0 < K; k0 += 64) {
    __syncthreads();  // previous compute's LDS reads complete
#pragma unroll
    for (int r = 0; r < 2; r++)
#pragma unroll
      for (int hf = 0; hf < 2; hf++) {
        lst8(AsD[r][hf], ra[r][hf]);
        lst8(BsD[r][hf], rb[r][hf]);
      }
    __syncthreads();  // tiles visible

    {  // prefetch next k-chunk under compute (clamped)
      const int kp = (k0 + 64 < K) ? k0 + 64 : k0;
#pragma unroll
      for (int r = 0; r < 2; r++)
#pragma unroll
        for (int hf = 0; hf < 2; hf++) {
          const float* pa = Ag + (long)r * 64 * K + kp + hf * 32;
          const float* pb = Bg + (long)r * 64 * K + kp + hf * 32;
          ra[r][hf] = pack8(*(const f32x4*)pa, *(const f32x4*)(pa + 4));
          rb[r][hf] = pack8(*(const f32x4*)pb, *(const f32x4*)(pb + 4));
        }
    }

#pragma unroll
    for (int hf = 0; hf < 2; hf++) {
      bf16x8 a[4], b[4];
#pragma unroll
      for (int i = 0; i < 4; i++)
        a[i] = ldsld8(&As[hf][(wr * 64 + i * 16 + lane15) * 32 + quad * 8]);
#pragma unroll
      for (int j = 0; j < 4; j++)
        b[j] = ldsld8(&Bs[hf][(wc * 64 + j * 16 + lane15) * 32 + quad * 8]);
#pragma unroll
      for (int i = 0; i < 4; i++)
#pragma unroll
        for (int j = 0; j < 4; j++) acc[i][j] = mfma16(a[i], b[j], acc[i][j]);
    }
  }

  // epilogue: C/D layout col=lane&15, row=quad*4+reg
#pragma unroll
  for (int i = 0; i < 4; i++)
#pragma unroll
    for (int j = 0; j < 4; j++) {
      const int col = col0 + wc * 64 + j * 16 + lane15;
#pragma unroll
      for (int r = 0; r < 4; r++) {
        const long row = row0 + wr * 64 + i * 16 + quad * 4 + r;
        C[row * (long)N + col] = f2b(acc[i][j][r]);
      }
    }
}

// ---------------------------------------------------------------------------
// gemm3: C[M,512](fp32) = A[M,512](bf16) @ Bt[512,512](fp32)^T + bias.
// BM=128, BN=64, BK=64. A via async16; B reg-prefetch + cvt. (R8-unchanged)
// ---------------------------------------------------------------------------
__global__ void gemm_b64(const u16* __restrict__ A, const float* __restrict__ Bt,
                         const float* __restrict__ bias, float* __restrict__ C,
                         int N, int K) {
  __shared__ __align__(16) u16 As[2][128 * 32];
  __shared__ __align__(16) u16 Bs[2][64 * 32];

  const int t = threadIdx.x, lane = t & 63, w = t >> 6;
  const int lane15 = lane & 15, quad = lane >> 4;
  const int wr = w >> 1, wc = w & 1;
  const long row0 = (long)blockIdx.y * 128;
  const int col0 = blockIdx.x * 64;

  const int srow = w * 16 + (lane >> 2);
  const int scol = (lane & 3) * 8;
  const u16* Ag = A + (row0 + srow) * (long)K + scol;

  const int brow = t >> 2, bc = (t & 3) * 16;
  const float* Bg = Bt + (long)(col0 + brow) * K + bc;
  u16* BsD = &Bs[bc >> 5][brow * 32 + (bc & 31)];

  f32x4 acc[4][2];
#pragma unroll
  for (int i = 0; i < 4; i++)
#pragma unroll
    for (int j = 0; j < 2; j++) acc[i][j] = (f32x4)(0.0f);

  f32x4 q0 = *(const f32x4*)Bg, q1 = *(const f32x4*)(Bg + 4);
  f32x4 q2 = *(const f32x4*)(Bg + 8), q3 = *(const f32x4*)(Bg + 12);

  for (int k0 = 0; k0 < K; k0 += 64) {
    __syncthreads();
#pragma unroll
    for (int r = 0; r < 2; r++)
#pragma unroll
      for (int hf = 0; hf < 2; hf++)
        async16(Ag + (long)r * 64 * K + k0 + hf * 32,
                &As[hf][(r * 64 + w * 16) * 32]);
    lst8(BsD, pack8(q0, q1));
    lst8(BsD + 8, pack8(q2, q3));
    __syncthreads();

    {
      const int kp = (k0 + 64 < K) ? k0 + 64 : k0;
      q0 = *(const f32x4*)(Bg + kp);     q1 = *(const f32x4*)(Bg + kp + 4);
      q2 = *(const f32x4*)(Bg + kp + 8); q3 = *(const f32x4*)(Bg + kp + 12);
    }

#pragma unroll
    for (int hf = 0; hf < 2; hf++) {
      bf16x8 a[4], b[2];
#pragma unroll
      for (int i = 0; i < 4; i++)
        a[i] = ldsld8(&As[hf][(wr * 64 + i * 16 + lane15) * 32 + quad * 8]);
#pragma unroll
      for (int j = 0; j < 2; j++)
        b[j] = ldsld8(&Bs[hf][(wc * 32 + j * 16 + lane15) * 32 + quad * 8]);
#pragma unroll
      for (int i = 0; i < 4; i++)
#pragma unroll
        for (int j = 0; j < 2; j++) acc[i][j] = mfma16(a[i], b[j], acc[i][j]);
    }
  }

#pragma unroll
  for (int i = 0; i < 4; i++)
#pragma unroll
    for (int j = 0; j < 2; j++) {
      const int col = col0 + wc * 32 + j * 16 + lane15;
      const float bv = bias[col];
#pragma unroll
      for (int r = 0; r < 4; r++) {
        const long row = row0 + wr * 64 + i * 16 + quad * 4 + r;
        C[row * (long)N + col] = acc[i][j][r] + bv;
      }
    }
}

// ---------------------------------------------------------------------------
// Causal flash attention v4: Q-tile 128 (512 threads, 8 waves; wave w owns
// q-rows qt*128+w*16..+16), s-tile 64. Halves per-CU iterations (66->34) and
// K/V traffic vs v3. No-max softmax (bounded scores), single end reduction.
// ---------------------------------------------------------------------------
__global__ void attn_v4(const u16* __restrict__ qkv, u16* __restrict__ out) {
  constexpr int T = 2048, LD = 1536;
  constexpr float CEXP = 0.18033688f;  // 0.125 * log2(e)
  __shared__ __align__(16) u16 Ks[64 * 72];
  __shared__ __align__(16) u16 Vt[64 * 72];
  __shared__ __align__(16) u16 Ps[8][16 * 72];

  const int t = threadIdx.x, lane = t & 63, w = t >> 6;  // w in 0..7
  const int lane15 = lane & 15, quad = lane >> 4;

  const int i = blockIdx.x;
  int qt = i & 15;
  if (i >= 256) qt = 15 - qt;  // balance: CU pair {qt, 15-qt} -> 34 iters const
  const int h = (i >> 4) & 7;
  const int b = (i >> 7) & 3;
  const long base = (long)b * T * LD;

  // Q A-frags straight from global
  const u16* gq =
      qkv + base + (long)(qt * 128 + w * 16 + lane15) * LD + h * 64 + quad * 8;
  const bf16x8 qa0 = __builtin_bit_cast(bf16x8, *(const u16x8*)gq);
  const bf16x8 qa1 = __builtin_bit_cast(bf16x8, *(const u16x8*)(gq + 32));

  // staging maps (512 threads: one K-row chunk + one V-row chunk per thread)
  const int srow = t >> 3, sc8 = (t & 7) * 8;  // K rows 0..63
  const int vs = t >> 3, vd0 = (t & 7) * 8;    // V s=vs, dims vd0..+8

  const int nsb = 2 * qt + 2;

  u16x8 kr, vr;  // prefetch s-tile 0
  {
    const u16* gk = qkv + base + (long)srow * LD + 512 + h * 64 + sc8;
    const u16* gv = qkv + base + (long)vs * LD + 1024 + h * 64 + vd0;
    kr = gld8(gk);
    vr = gld8(gv);
  }

  float lp[4] = {0.0f, 0.0f, 0.0f, 0.0f};
  f32x4 o[4];
#pragma unroll
  for (int j = 0; j < 4; j++) o[j] = (f32x4)(0.0f);

  const int qrow_base = qt * 128 + w * 16 + quad * 4;  // + r
  const int qrow_wave_max = qt * 128 + w * 16 + 15;

  for (int sb = 0; sb < nsb; ++sb) {
    __syncthreads();  // previous iteration's LDS reads complete
    lst8(&Ks[srow * 72 + sc8], kr);
#pragma unroll
    for (int ii = 0; ii < 8; ii++) {
      const int d = vd0 + ii;
      Vt[d * 72 + (vs ^ (((d >> 3) & 7) << 3))] = vr[ii];
    }
    __syncthreads();  // tiles visible

    {  // prefetch next s-tile under compute (clamped)
      const int sp = (sb + 1 < nsb) ? sb + 1 : sb;
      const u16* gk = qkv + base + (long)(sp * 64 + srow) * LD + 512 + h * 64 + sc8;
      const u16* gv = qkv + base + (long)(sp * 64 + vs) * LD + 1024 + h * 64 + vd0;
      kr = gld8(gk);
      vr = gld8(gv);
    }

    if (sb * 64 > qrow_wave_max) continue;  // whole wave masked (uniform)

    // S strip (16 q x 64 s)
    f32x4 sf[4];
#pragma unroll
    for (int j = 0; j < 4; j++) {
      f32x4 z = (f32x4)(0.0f);
      z = mfma16(qa0, ldsld8(&Ks[(j * 16 + lane15) * 72 + quad * 8]), z);
      sf[j] = mfma16(qa1, ldsld8(&Ks[(j * 16 + lane15) * 72 + quad * 8 + 32]), z);
    }

    if (sb >= 2 * qt) {  // diagonal zone: per-element causal mask
      const int scol_base = sb * 64 + lane15;
#pragma unroll
      for (int j = 0; j < 4; j++)
#pragma unroll
        for (int r = 0; r < 4; r++) {
          float p = exp2f(sf[j][r] * CEXP);
          if (scol_base + j * 16 > qrow_base + r) p = 0.0f;
          sf[j][r] = p;
          lp[r] += p;
        }
    } else {
#pragma unroll
      for (int j = 0; j < 4; j++)
#pragma unroll
        for (int r = 0; r < 4; r++) {
          const float p = exp2f(sf[j][r] * CEXP);
          sf[j][r] = p;
          lp[r] += p;
        }
    }

    // P: C-layout -> per-wave LDS chunk -> A-layout (same-wave DS in-order)
    u16* myP = Ps[w];
#pragma unroll
    for (int j = 0; j < 4; j++)
#pragma unroll
      for (int r = 0; r < 4; r++)
        myP[(quad * 4 + r) * 72 + j * 16 + lane15] = f2b(sf[j][r]);
    __asm__ __volatile__("" ::: "memory");
    const bf16x8 pa0 = ldsld8(&myP[lane15 * 72 + quad * 8]);
    const bf16x8 pa1 = ldsld8(&myP[lane15 * 72 + quad * 8 + 32]);
    __asm__ __volatile__("" ::: "memory");

    // O += P @ V from swizzled Vt
#pragma unroll
    for (int j = 0; j < 4; j++) {
      const int d0 = j * 16 + lane15;
      const int swz = ((d0 >> 3) & 7) << 3;
      o[j] = mfma16(pa0, ldsld8(&Vt[d0 * 72 + ((quad * 8) ^ swz)]), o[j]);
      o[j] = mfma16(pa1, ldsld8(&Vt[d0 * 72 + ((quad * 8 + 32) ^ swz)]), o[j]);
    }
  }

  // single cross-lane row-sum reduction, then store
#pragma unroll
  for (int off = 1; off < 16; off <<= 1)
#pragma unroll
    for (int r = 0; r < 4; r++) lp[r] += __shfl_xor(lp[r], off);

  const long orow0 = (long)b * T + qt * 128 + w * 16;
  float inv[4];
#pragma unroll
  for (int r = 0; r < 4; r++) inv[r] = 1.0f / lp[r];
#pragma unroll
  for (int j = 0; j < 4; j++)
#pragma unroll
    for (int r = 0; r < 4; r++)
      out[(orow0 + quad * 4 + r) * 512 + h * 64 + j * 16 + lane15] =
          f2b(o[j][r] * inv[r]);
}

// ---------------------------------------------------------------------------
extern "C" void kernel_launch(void* const* d_in, const int* in_sizes, int n_in,
                              void* d_out, int out_size, void* d_ws, size_t ws_size,
                              hipStream_t stream) {
  const float* x      = (const float*)d_in[0];  // [4,2048,512] fp32
  const float* w_qkv  = (const float*)d_in[1];  // [1536,512]  fp32
  const float* w_proj = (const float*)d_in[2];  // [512,512]   fp32
  const float* b_proj = (const float*)d_in[3];  // [512]       fp32
  float* out = (float*)d_out;                   // [4,2048,512] fp32

  u16* qkv  = (u16*)d_ws;                  // [8192 x 1536] bf16 = 24 MiB
  u16* attn = qkv + (size_t)8192 * 1536;   // [8192 x 512]  bf16 =  8 MiB

  // [1] qkv projection with fused fp32->bf16 conversion
  gemm1f<<<dim3(12, 64), 256, 0, stream>>>(x, w_qkv, qkv, 1536, 512);
  // [2] causal flash attention (Q-tile 128)
  attn_v4<<<512, 512, 0, stream>>>(qkv, attn);
  // [3] output projection + bias -> fp32 d_out
  gemm_b64<<<dim3(8, 64), 256, 0, stream>>>(attn, w_proj, b_proj, out, 512, 512);
}

// Round 11
// 165.862 us; speedup vs baseline: 1.4035x; 1.4035x over previous
//
#include <hip/hip_runtime.h>
#include <hip/hip_bf16.h>

// MultiHeadAttention: B=4, T=2048, D=512, H=8, K=64.
// Inputs fp32, output fp32, intermediates bf16.
// [0] cvt {x, w_qkv} -> bf16   [1] gemm_bb256: qkv = x @ w_qkv^T (BN=256)
// [2] attn_v3 (R7/R8-proven)   [3] gemm_b64: out = attn @ w_proj^T + b_proj
//
// R11: fused-cvt gemm1 reverted (it re-fetched fp32 12x -> 100 µs, HBM-bound).
// GEMM side is TRAFFIC-bound: fix = bf16 operands + bigger BN (A-refetch 12->6).

typedef unsigned short u16;
typedef __attribute__((ext_vector_type(8))) __bf16 bf16x8;
typedef __attribute__((ext_vector_type(8))) unsigned short u16x8;
typedef __attribute__((ext_vector_type(4))) float f32x4;
typedef __attribute__((ext_vector_type(4))) unsigned u32x4;

#define DEV static __device__ __forceinline__

DEV void async16(const u16* g, u16* l) {  // global->LDS DMA, 16B/lane
  __builtin_amdgcn_global_load_lds(
      (const __attribute__((address_space(1))) unsigned int*)g,
      (__attribute__((address_space(3))) unsigned int*)l, 16, 0, 0);
}
DEV u16x8 gld8(const u16* p) { return *(const u16x8*)p; }
DEV void lst8(u16* p, u16x8 v) { *(u16x8*)p = v; }
DEV bf16x8 ldsld8(const u16* p) {
  return __builtin_bit_cast(bf16x8, *(const u16x8*)p);
}
DEV f32x4 mfma16(bf16x8 a, bf16x8 b, f32x4 c) {
  return __builtin_amdgcn_mfma_f32_16x16x32_bf16(a, b, c, 0, 0, 0);
}
DEV u16 f2b(float f) {  // fp32 -> bf16 RNE
  unsigned u = __builtin_bit_cast(unsigned, f);
  u += 0x7FFFu + ((u >> 16) & 1u);
  return (u16)(u >> 16);
}
DEV unsigned pk2(float x, float y) {  // v_cvt_pk_bf16_f32
  __hip_bfloat162 t = __float22bfloat162_rn(float2{x, y});
  unsigned r;
  __builtin_memcpy(&r, &t, 4);
  return r;
}
DEV u16x8 pack8(f32x4 a, f32x4 b) {
  u32x4 t;
  t[0] = pk2(a[0], a[1]);
  t[1] = pk2(a[2], a[3]);
  t[2] = pk2(b[0], b[1]);
  t[3] = pk2(b[2], b[3]);
  return __builtin_bit_cast(u16x8, t);
}

// ---------------------------------------------------------------------------
// fp32 -> bf16: x (8192x512) -> xb, w_qkv (1536x512) -> wqb (parked in d_out)
__global__ void cvt_all(const float* __restrict__ x, const float* __restrict__ wq,
                        u16* __restrict__ xb, u16* __restrict__ wqb) {
  constexpr long NX = 8192L * 512 / 8;  // 524288
  constexpr long NQ = 1536L * 512 / 8;  // 98304
  const long i = (long)blockIdx.x * 256 + threadIdx.x;
  if (i < NX) {
    const float* p = x + i * 8;
    *(u16x8*)(xb + i * 8) = pack8(*(const f32x4*)p, *(const f32x4*)(p + 4));
  } else if (i < NX + NQ) {
    const long j = i - NX;
    const float* p = wq + j * 8;
    *(u16x8*)(wqb + j * 8) = pack8(*(const f32x4*)p, *(const f32x4*)(p + 4));
  }
}

// ---------------------------------------------------------------------------
// gemm1: C[M,1536](bf16) = A[M,512](bf16) @ Bt[1536,512](bf16)^T.
// BM=128, BN=256, BK=64 (two 32-halves), both via async16.
// 512 threads = 8 waves as 2x4; wave tile 64x64, 4x4 frags of 16x16x32.
// A-refetch = N/BN = 6 (was 12) -> HBM traffic ~halved on the A side.
// ---------------------------------------------------------------------------
__global__ void gemm_bb256(const u16* __restrict__ A, const u16* __restrict__ Bt,
                           u16* __restrict__ C, int N, int K) {
  __shared__ __align__(16) u16 As[2][128 * 32];
  __shared__ __align__(16) u16 Bs[2][256 * 32];

  const int t = threadIdx.x, lane = t & 63, w = t >> 6;  // w 0..7
  const int lane15 = lane & 15, quad = lane >> 4;
  const int wr = w >> 2, wc = w & 3;  // 2 x 4 wave grid
  const long row0 = (long)blockIdx.y * 128;
  const int col0 = blockIdx.x * 256;

  // staging: one async16 = 16 rows x 32 cols (row = base + lane/4, col=(lane&3)*8)
  const int lrow = lane >> 2, lcol = (lane & 3) * 8;
  const u16* Ag = A + (row0 + w * 16 + lrow) * (long)K + lcol;     // rows w*16..+16
  const u16* Bg = Bt + ((long)col0 + w * 32 + lrow) * (long)K + lcol;  // rows w*32..+32

  f32x4 acc[4][4];
#pragma unroll
  for (int i = 0; i < 4; i++)
#pragma unroll
    for (int j = 0; j < 4; j++) acc[i][j] = (f32x4)(0.0f);

  for (int k0 = 0; k0 < K; k0 += 64) {
    __syncthreads();  // previous compute's LDS reads complete
#pragma unroll
    for (int hf = 0; hf < 2; hf++) {
      async16(Ag + k0 + hf * 32, &As[hf][(w * 16) * 32]);
#pragma unroll
      for (int rr = 0; rr < 2; rr++)
        async16(Bg + (long)rr * 16 * K + k0 + hf * 32,
                &Bs[hf][(w * 32 + rr * 16) * 32]);
    }
    __syncthreads();  // vmcnt drain -> tiles visible

#pragma unroll
    for (int hf = 0; hf < 2; hf++) {
      bf16x8 a[4], b[4];
#pragma unroll
      for (int i = 0; i < 4; i++)
        a[i] = ldsld8(&As[hf][(wr * 64 + i * 16 + lane15) * 32 + quad * 8]);
#pragma unroll
      for (int j = 0; j < 4; j++)
        b[j] = ldsld8(&Bs[hf][(wc * 64 + j * 16 + lane15) * 32 + quad * 8]);
#pragma unroll
      for (int i = 0; i < 4; i++)
#pragma unroll
        for (int j = 0; j < 4; j++) acc[i][j] = mfma16(a[i], b[j], acc[i][j]);
    }
  }

  // epilogue: C/D layout col=lane&15, row=quad*4+reg
#pragma unroll
  for (int i = 0; i < 4; i++)
#pragma unroll
    for (int j = 0; j < 4; j++) {
      const int col = col0 + wc * 64 + j * 16 + lane15;
#pragma unroll
      for (int r = 0; r < 4; r++) {
        const long row = row0 + wr * 64 + i * 16 + quad * 4 + r;
        C[row * (long)N + col] = f2b(acc[i][j][r]);
      }
    }
}

// ---------------------------------------------------------------------------
// gemm3: C[M,512](fp32) = A[M,512](bf16) @ Bt[512,512](fp32)^T + bias.
// BM=128, BN=64, BK=64. A via async16; B reg-prefetch + cvt. (R8-proven)
// ---------------------------------------------------------------------------
__global__ void gemm_b64(const u16* __restrict__ A, const float* __restrict__ Bt,
                         const float* __restrict__ bias, float* __restrict__ C,
                         int N, int K) {
  __shared__ __align__(16) u16 As[2][128 * 32];
  __shared__ __align__(16) u16 Bs[2][64 * 32];

  const int t = threadIdx.x, lane = t & 63, w = t >> 6;
  const int lane15 = lane & 15, quad = lane >> 4;
  const int wr = w >> 1, wc = w & 1;
  const long row0 = (long)blockIdx.y * 128;
  const int col0 = blockIdx.x * 64;

  const int srow = w * 16 + (lane >> 2);
  const int scol = (lane & 3) * 8;
  const u16* Ag = A + (row0 + srow) * (long)K + scol;

  const int brow = t >> 2, bc = (t & 3) * 16;
  const float* Bg = Bt + (long)(col0 + brow) * K + bc;
  u16* BsD = &Bs[bc >> 5][brow * 32 + (bc & 31)];

  f32x4 acc[4][2];
#pragma unroll
  for (int i = 0; i < 4; i++)
#pragma unroll
    for (int j = 0; j < 2; j++) acc[i][j] = (f32x4)(0.0f);

  f32x4 q0 = *(const f32x4*)Bg, q1 = *(const f32x4*)(Bg + 4);
  f32x4 q2 = *(const f32x4*)(Bg + 8), q3 = *(const f32x4*)(Bg + 12);

  for (int k0 = 0; k0 < K; k0 += 64) {
    __syncthreads();
#pragma unroll
    for (int r = 0; r < 2; r++)
#pragma unroll
      for (int hf = 0; hf < 2; hf++)
        async16(Ag + (long)r * 64 * K + k0 + hf * 32,
                &As[hf][(r * 64 + w * 16) * 32]);
    lst8(BsD, pack8(q0, q1));
    lst8(BsD + 8, pack8(q2, q3));
    __syncthreads();

    {
      const int kp = (k0 + 64 < K) ? k0 + 64 : k0;
      q0 = *(const f32x4*)(Bg + kp);     q1 = *(const f32x4*)(Bg + kp + 4);
      q2 = *(const f32x4*)(Bg + kp + 8); q3 = *(const f32x4*)(Bg + kp + 12);
    }

#pragma unroll
    for (int hf = 0; hf < 2; hf++) {
      bf16x8 a[4], b[2];
#pragma unroll
      for (int i = 0; i < 4; i++)
        a[i] = ldsld8(&As[hf][(wr * 64 + i * 16 + lane15) * 32 + quad * 8]);
#pragma unroll
      for (int j = 0; j < 2; j++)
        b[j] = ldsld8(&Bs[hf][(wc * 32 + j * 16 + lane15) * 32 + quad * 8]);
#pragma unroll
      for (int i = 0; i < 4; i++)
#pragma unroll
        for (int j = 0; j < 2; j++) acc[i][j] = mfma16(a[i], b[j], acc[i][j]);
    }
  }

#pragma unroll
  for (int i = 0; i < 4; i++)
#pragma unroll
    for (int j = 0; j < 2; j++) {
      const int col = col0 + wc * 32 + j * 16 + lane15;
      const float bv = bias[col];
#pragma unroll
      for (int r = 0; r < 4; r++) {
        const long row = row0 + wr * 64 + i * 16 + quad * 4 + r;
        C[row * (long)N + col] = acc[i][j][r] + bv;
      }
    }
}

// ---------------------------------------------------------------------------
// Causal flash attention v3 (R7/R8-proven, ~59.5 µs).
// ---------------------------------------------------------------------------
__global__ void attn_v3(const u16* __restrict__ qkv, u16* __restrict__ out) {
  constexpr int T = 2048, LD = 1536;
  constexpr float CEXP = 0.18033688f;  // 0.125 * log2(e)
  __shared__ __align__(16) u16 Ks[64 * 72];
  __shared__ __align__(16) u16 Vt[64 * 72];
  __shared__ __align__(16) u16 Ps[4][16 * 72];

  const int t = threadIdx.x, lane = t & 63, w = t >> 6;
  const int lane15 = lane & 15, quad = lane >> 4;

  const int i = blockIdx.x;
  int qb = i & 31;
  if (i >= 512) qb = 31 - qb;  // load-balance
  const int h = (i >> 5) & 7;
  const int b = (i >> 8) & 3;
  const long base = (long)b * T * LD;

  const u16* gq =
      qkv + base + (long)(qb * 64 + w * 16 + lane15) * LD + h * 64 + quad * 8;
  const bf16x8 qa0 = __builtin_bit_cast(bf16x8, *(const u16x8*)gq);
  const bf16x8 qa1 = __builtin_bit_cast(bf16x8, *(const u16x8*)(gq + 32));

  const int srow = t >> 3, sc8 = (t & 7) * 8;
  const int vs = t >> 2, vd0 = (t & 3) * 16;

  const int nsb = qb + 1;

  u16x8 kr0, kr1, vr0, vr1;
  {
    const u16* gk = qkv + base + (long)srow * LD + 512 + h * 64 + sc8;
    const u16* gv = qkv + base + (long)vs * LD + 1024 + h * 64 + vd0;
    kr0 = gld8(gk); kr1 = gld8(gk + (long)32 * LD);
    vr0 = gld8(gv); vr1 = gld8(gv + 8);
  }

  float lp[4] = {0.0f, 0.0f, 0.0f, 0.0f};
  f32x4 o[4];
#pragma unroll
  for (int j = 0; j < 4; j++) o[j] = (f32x4)(0.0f);

  const int qrow_base = qb * 64 + w * 16 + quad * 4;

  for (int sb = 0; sb < nsb; ++sb) {
    __syncthreads();
    lst8(&Ks[srow * 72 + sc8], kr0);
    lst8(&Ks[(srow + 32) * 72 + sc8], kr1);
#pragma unroll
    for (int ii = 0; ii < 8; ii++) {
      const int d = vd0 + ii;
      Vt[d * 72 + (vs ^ (((d >> 3) & 7) << 3))] = vr0[ii];
    }
#pragma unroll
    for (int ii = 0; ii < 8; ii++) {
      const int d = vd0 + 8 + ii;
      Vt[d * 72 + (vs ^ (((d >> 3) & 7) << 3))] = vr1[ii];
    }
    __syncthreads();

    {
      const int sp = (sb + 1 < nsb) ? sb + 1 : sb;
      const u16* gk = qkv + base + (long)(sp * 64 + srow) * LD + 512 + h * 64 + sc8;
      const u16* gv = qkv + base + (long)(sp * 64 + vs) * LD + 1024 + h * 64 + vd0;
      kr0 = gld8(gk); kr1 = gld8(gk + (long)32 * LD);
      vr0 = gld8(gv); vr1 = gld8(gv + 8);
    }

    f32x4 sf[4];
#pragma unroll
    for (int j = 0; j < 4; j++) {
      f32x4 z = (f32x4)(0.0f);
      z = mfma16(qa0, ldsld8(&Ks[(j * 16 + lane15) * 72 + quad * 8]), z);
      sf[j] = mfma16(qa1, ldsld8(&Ks[(j * 16 + lane15) * 72 + quad * 8 + 32]), z);
    }

    if (sb == qb) {
      const int scol_base = sb * 64 + lane15;
#pragma unroll
      for (int j = 0; j < 4; j++)
#pragma unroll
        for (int r = 0; r < 4; r++) {
          float p = exp2f(sf[j][r] * CEXP);
          if (scol_base + j * 16 > qrow_base + r) p = 0.0f;
          sf[j][r] = p;
          lp[r] += p;
        }
    } else {
#pragma unroll
      for (int j = 0; j < 4; j++)
#pragma unroll
        for (int r = 0; r < 4; r++) {
          const float p = exp2f(sf[j][r] * CEXP);
          sf[j][r] = p;
          lp[r] += p;
        }
    }

    u16* myP = Ps[w];
#pragma unroll
    for (int j = 0; j < 4; j++)
#pragma unroll
      for (int r = 0; r < 4; r++)
        myP[(quad * 4 + r) * 72 + j * 16 + lane15] = f2b(sf[j][r]);
    __asm__ __volatile__("" ::: "memory");
    const bf16x8 pa0 = ldsld8(&myP[lane15 * 72 + quad * 8]);
    const bf16x8 pa1 = ldsld8(&myP[lane15 * 72 + quad * 8 + 32]);
    __asm__ __volatile__("" ::: "memory");

#pragma unroll
    for (int j = 0; j < 4; j++) {
      const int d0 = j * 16 + lane15;
      const int swz = ((d0 >> 3) & 7) << 3;
      o[j] = mfma16(pa0, ldsld8(&Vt[d0 * 72 + ((quad * 8) ^ swz)]), o[j]);
      o[j] = mfma16(pa1, ldsld8(&Vt[d0 * 72 + ((quad * 8 + 32) ^ swz)]), o[j]);
    }
  }

#pragma unroll
  for (int off = 1; off < 16; off <<= 1)
#pragma unroll
    for (int r = 0; r < 4; r++) lp[r] += __shfl_xor(lp[r], off);

  const long orow0 = (long)b * T + qb * 64 + w * 16;
  float inv[4];
#pragma unroll
  for (int r = 0; r < 4; r++) inv[r] = 1.0f / lp[r];
#pragma unroll
  for (int j = 0; j < 4; j++)
#pragma unroll
    for (int r = 0; r < 4; r++)
      out[(orow0 + quad * 4 + r) * 512 + h * 64 + j * 16 + lane15] =
          f2b(o[j][r] * inv[r]);
}

// ---------------------------------------------------------------------------
extern "C" void kernel_launch(void* const* d_in, const int* in_sizes, int n_in,
                              void* d_out, int out_size, void* d_ws, size_t ws_size,
                              hipStream_t stream) {
  const float* x      = (const float*)d_in[0];  // [4,2048,512] fp32
  const float* w_qkv  = (const float*)d_in[1];  // [1536,512]  fp32
  const float* w_proj = (const float*)d_in[2];  // [512,512]   fp32
  const float* b_proj = (const float*)d_in[3];  // [512]       fp32
  float* out = (float*)d_out;                   // [4,2048,512] fp32

  u16* qkv = (u16*)d_ws;                  // [8192 x 1536] bf16 = 24 MiB
  u16* xb  = qkv + (size_t)8192 * 1536;   // [8192 x 512]  bf16 =  8 MiB
                                          // (x_bf16, then attn output)
  u16* wqb = (u16*)d_out;                 // w_qkv bf16 (1.5 MiB) parked in
                                          // d_out — dead until gemm3 writes

  // [0] convert x and w_qkv to bf16
  cvt_all<<<2432, 256, 0, stream>>>(x, w_qkv, xb, wqb);
  // [1] qkv projection (all-bf16, BN=256)
  gemm_bb256<<<dim3(6, 64), 512, 0, stream>>>(xb, wqb, qkv, 1536, 512);
  // [2] causal flash attention (overwrites xb)
  attn_v3<<<1024, 256, 0, stream>>>(qkv, xb);
  // [3] output projection + bias -> fp32 d_out
  gemm_b64<<<dim3(8, 64), 256, 0, stream>>>(xb, w_proj, b_proj, out, 512, 512);
}